// Round 12
// baseline (435.136 us; speedup 1.0000x reference)
//
#include <hip/hip_runtime.h>
#include <stdint.h>

// Problem constants
#define BB 4
#define LL 2048
#define QQ 16293
#define RR 24
#define DD 32
#define SS 128
#define NLAYER 8
#define OUTW 1792
#define TT0 2047              // length of x after embedding (L-1)
#define MROWS (BB*OUTW)       // 7168
#define NPAD 16384            // padded Q for GEMM tiles
#define WCH 28                // skip rows per fused-layer block (64 blocks/batch)

typedef float v4f __attribute__((ext_vector_type(4)));
typedef short v8s __attribute__((ext_vector_type(8)));

static __device__ __forceinline__ unsigned short f2bf(float x) {
  unsigned int u = __float_as_uint(x);
  unsigned int r = (u + 0x7fffu + ((u >> 16) & 1u)) >> 16;
  return (unsigned short)r;
}

static __device__ __forceinline__ float fast_sigmoid(float z) {
  return __builtin_amdgcn_rcpf(1.0f + __expf(-z));
}
static __device__ __forceinline__ float fast_tanh(float z) {
  return 1.0f - 2.0f * __builtin_amdgcn_rcpf(1.0f + __expf(2.0f * z));
}

// ---------------------------------------------------------------------------
// Fused layers v3: ALL per-layer weights (filt+gate+res+skip, 34KB/layer)
// double-buffered in LDS, prefetched one layer ahead (loads issued at the
// top of phase 2, ds_written at its end -> HBM/L2 latency hidden under
// skip+res math). Compute phases read weights only via LDS broadcasts; no
// post-barrier scalar-load stall chains. LDS total ~83KB; grid 256 blocks
// on 256 CUs (1/CU), so the LDS growth costs nothing.
// ---------------------------------------------------------------------------
__global__ __launch_bounds__(1024) void fused_layers_kernel(
    const int* __restrict__ idx, const float* __restrict__ preW,
    const float* __restrict__ filtW, const float* __restrict__ gateW,
    const float* __restrict__ resW, const float* __restrict__ skipW,
    float* __restrict__ skip_out) {
  int b = blockIdx.y;
  int j0 = blockIdx.x * WCH;
  int tid = (int)threadIdx.x;
  int lane = tid & 63;
  int w = __builtin_amdgcn_readfirstlane(tid >> 6);

  __shared__ float x_t[2][RR][66];   // 12.7KB
  __shared__ float out_s[64][33];    //  8.4KB
  __shared__ float wF[2][2 * RR * DD];  // 12KB  filt [tap][r][d]
  __shared__ float wG[2][2 * RR * DD];  // 12KB  gate
  __shared__ float wR[2][DD * RR];      //  6KB  res  [d][r]
  __shared__ float wS[2][DD * SS];      // 32KB  skip [d][s]

  for (int z = tid; z < 2 * RR * 2; z += 1024) {
    int bu = z & 1;
    int cc = 64 + ((z >> 1) & 1);
    int r = z >> 2;
    x_t[bu][r][cc] = 0.f;
  }

  // ---- issue layer-0 weight loads (registers), then embedding, then write
  float pf[8];
  {
    const float* Fs = filtW;
    const float* Gs = gateW;
    pf[0] = Fs[tid];
    pf[1] = (tid < 512) ? Fs[1024 + tid] : Gs[tid - 512];
    pf[2] = Gs[512 + tid];
    pf[3] = (tid < DD * RR) ? resW[tid] : 0.f;
    const float2* S2 = (const float2*)skipW;
#pragma unroll
    for (int k = 0; k < 2; ++k) {
      float2 v = S2[k * 1024 + tid];
      pf[4 + 2 * k] = v.x;
      pf[5 + 2 * k] = v.y;
    }
  }

  int tbase = j0 + 247;
  if (w < 12) {
    int t = tbase + lane;
    if (t > TT0 - 1) t = TT0 - 1;
    int i0 = idx[b * LL + t];
    int i1 = idx[b * LL + t + 1];
    const float* p0 = preW + (size_t)i0 * RR + 2 * w;
    const float* p1 = preW + (size_t)QQ * RR + (size_t)i1 * RR + 2 * w;
#pragma unroll
    for (int rr = 0; rr < 2; ++rr)
      x_t[0][2 * w + rr][lane] = p0[rr] + p1[rr];
  }

  // ---- write layer-0 weights to LDS buf 0
  {
    wF[0][tid] = pf[0];
    if (tid < 512) wF[0][1024 + tid] = pf[1]; else wG[0][tid - 512] = pf[1];
    wG[0][512 + tid] = pf[2];
    if (tid < DD * RR) wR[0][tid] = pf[3];
#pragma unroll
    for (int k = 0; k < 2; ++k) {
      wS[0][(k * 1024 + tid) * 2 + 0] = pf[4 + 2 * k];
      wS[0][(k * 1024 + tid) * 2 + 1] = pf[5 + 2 * k];
    }
  }

  float sk00 = 0.f, sk01 = 0.f, sk10 = 0.f, sk11 = 0.f;

  __syncthreads();

  for (int i = 0; i < NLAYER; ++i) {
    int cur = i & 1, nxt = cur ^ 1;
    int lmax = 62 - i;

    // ---- conv phase: weights from LDS (wave-uniform broadcast reads)
    float xa[RR], xb[RR];
#pragma unroll
    for (int r = 0; r < RR; ++r) {
      xa[r] = x_t[cur][r][lane];
      xb[r] = x_t[cur][r][lane + 1];
    }
    float zf[2], zg[2];
#pragma unroll
    for (int dd = 0; dd < 2; ++dd) { zf[dd] = 0.f; zg[dd] = 0.f; }
#pragma unroll
    for (int r = 0; r < RR; ++r) {
#pragma unroll
      for (int dd = 0; dd < 2; ++dd) {
        int d = w * 2 + dd;
        zf[dd] = fmaf(xa[r], wF[cur][r * DD + d], zf[dd]);
        zf[dd] = fmaf(xb[r], wF[cur][RR * DD + r * DD + d], zf[dd]);
        zg[dd] = fmaf(xa[r], wG[cur][r * DD + d], zg[dd]);
        zg[dd] = fmaf(xb[r], wG[cur][RR * DD + r * DD + d], zg[dd]);
      }
    }
    if (lane <= lmax) {
#pragma unroll
      for (int dd = 0; dd < 2; ++dd)
        out_s[lane][w * 2 + dd] = fast_tanh(zf[dd]) * fast_sigmoid(zg[dd]);
    }
    __syncthreads();

    // ---- phase 2: issue next-layer weight loads FIRST (latency hides
    // under skip+res math), ds_write at the end (T14 split).
    bool do_pf = (i + 1 < NLAYER);
    if (do_pf) {
      const float* Fs = filtW + (size_t)(i + 1) * 2 * RR * DD;
      const float* Gs = gateW + (size_t)(i + 1) * 2 * RR * DD;
      pf[0] = Fs[tid];
      pf[1] = (tid < 512) ? Fs[1024 + tid] : Gs[tid - 512];
      pf[2] = Gs[512 + tid];
      pf[3] = (tid < DD * RR) ? resW[(size_t)(i + 1) * DD * RR + tid] : 0.f;
      const float2* S2 = (const float2*)(skipW + (size_t)(i + 1) * DD * SS);
#pragma unroll
      for (int k = 0; k < 2; ++k) {
        float2 v = S2[k * 1024 + tid];
        pf[4 + 2 * k] = v.x;
        pf[5 + 2 * k] = v.y;
      }
    }

    // ---- skip phase: wave w<14 -> rows {2w,2w+1}; lane -> cols {2l,2l+1}
    if (w < 14) {
      int jr = 2 * w + 7 - i;
#pragma unroll
      for (int d = 0; d < DD; ++d) {
        float o0 = out_s[jr][d];
        float o1 = out_s[jr + 1][d];
        float wx = wS[cur][d * SS + 2 * lane];
        float wy = wS[cur][d * SS + 2 * lane + 1];
        sk00 = fmaf(o0, wx, sk00);
        sk01 = fmaf(o0, wy, sk01);
        sk10 = fmaf(o1, wx, sk10);
        sk11 = fmaf(o1, wy, sk11);
      }
    }

    // ---- residual phase: weights from LDS broadcast
    if (w < 12 && lane <= lmax) {
#pragma unroll
      for (int rr = 0; rr < 2; ++rr) {
        int r = w * 2 + rr;
        float acc = x_t[cur][r][lane + 1];
#pragma unroll
        for (int d = 0; d < DD; ++d)
          acc = fmaf(out_s[lane][d], wR[cur][d * RR + r], acc);
        x_t[nxt][r][lane] = acc;
      }
    }

    // ---- ds_write prefetched weights (loads have had the whole phase)
    if (do_pf) {
      wF[nxt][tid] = pf[0];
      if (tid < 512) wF[nxt][1024 + tid] = pf[1]; else wG[nxt][tid - 512] = pf[1];
      wG[nxt][512 + tid] = pf[2];
      if (tid < DD * RR) wR[nxt][tid] = pf[3];
#pragma unroll
      for (int k = 0; k < 2; ++k) {
        wS[nxt][(k * 1024 + tid) * 2 + 0] = pf[4 + 2 * k];
        wS[nxt][(k * 1024 + tid) * 2 + 1] = pf[5 + 2 * k];
      }
    }
    __syncthreads();
  }

  // ---- write skip_sum: rows {2w,2w+1}, cols {2*lane,2*lane+1} coalesced
  if (w < 14) {
    size_t base = ((size_t)b * OUTW + j0 + 2 * w) * SS + 2 * lane;
    float2 v0; v0.x = sk00; v0.y = sk01;
    float2 v1; v1.x = sk10; v1.y = sk11;
    *(float2*)(skip_out + base) = v0;
    *(float2*)(skip_out + base + SS) = v1;
  }
}

// ---------------------------------------------------------------------------
// h1 = relu(relu(skip_sum) @ post_W1), stored bf16  [7168][128] (unchanged)
// ---------------------------------------------------------------------------
__global__ __launch_bounds__(256) void h1_kernel(const float* __restrict__ skip_sum,
                                                 const float* __restrict__ W1,
                                                 unsigned short* __restrict__ h1) {
  int m0 = blockIdx.x * 32;
  int tc = threadIdx.x & 31;
  int tr = threadIdx.x >> 5;
  __shared__ float h_s[32][128];
#pragma unroll
  for (int it = 0; it < 16; ++it) {
    int lin = it * 256 + (int)threadIdx.x;
    int rrow = lin >> 7, d = lin & 127;
    float v = skip_sum[(size_t)(m0 + rrow) * SS + d];
    h_s[rrow][d] = v > 0.f ? v : 0.f;
  }
  __syncthreads();

  float acc[4][4];
#pragma unroll
  for (int rr = 0; rr < 4; ++rr)
#pragma unroll
    for (int c = 0; c < 4; ++c) acc[rr][c] = 0.f;

#pragma unroll 4
  for (int d = 0; d < 128; ++d) {
    float4 wv = *(const float4*)(W1 + (size_t)d * SS + tc * 4);
#pragma unroll
    for (int rr = 0; rr < 4; ++rr) {
      float hv = h_s[tr * 4 + rr][d];
      acc[rr][0] = fmaf(hv, wv.x, acc[rr][0]);
      acc[rr][1] = fmaf(hv, wv.y, acc[rr][1]);
      acc[rr][2] = fmaf(hv, wv.z, acc[rr][2]);
      acc[rr][3] = fmaf(hv, wv.w, acc[rr][3]);
    }
  }
#pragma unroll
  for (int rr = 0; rr < 4; ++rr) {
    int row = m0 + tr * 4 + rr;
    ushort4 u;
    u.x = f2bf(fmaxf(acc[rr][0], 0.f));
    u.y = f2bf(fmaxf(acc[rr][1], 0.f));
    u.z = f2bf(fmaxf(acc[rr][2], 0.f));
    u.w = f2bf(fmaxf(acc[rr][3], 0.f));
    *(ushort4*)(h1 + (size_t)row * SS + tc * 4) = u;
  }
}

// ---------------------------------------------------------------------------
// W2T: transpose post_W2 [128][16293] -> bf16 [16384][128], zero-padded
// ---------------------------------------------------------------------------
__global__ __launch_bounds__(256) void w2t_kernel(const float* __restrict__ W2,
                                                  unsigned short* __restrict__ W2T) {
  int n0 = blockIdx.x * 64;
  __shared__ float t_s[64][129];
#pragma unroll
  for (int it = 0; it < 32; ++it) {
    int lin = it * 256 + (int)threadIdx.x;
    int k = lin >> 6, nn = lin & 63;
    int n = n0 + nn;
    t_s[nn][k] = (n < QQ) ? W2[(size_t)k * QQ + n] : 0.f;
  }
  __syncthreads();
#pragma unroll
  for (int it = 0; it < 4; ++it) {
    int lin = it * 256 + (int)threadIdx.x;
    int nn = lin >> 4, slot = lin & 15;
    v8s val;
#pragma unroll
    for (int jj = 0; jj < 8; ++jj) val[jj] = (short)f2bf(t_s[nn][slot * 8 + jj]);
    *(v8s*)(W2T + ((size_t)(n0 + nn)) * 128 + slot * 8) = val;
  }
}

// ---------------------------------------------------------------------------
// logits = h1 @ W2 (bf16 MFMA, fp32 accum). EXACT v1 kernel; this round
// launched with gridDim.z = 2 (identical work per z, same output written
// twice — deterministic) so ONE dispatch lasts ~315us and finally tops the
// rocprof table: need WRITE_SIZE / FETCH_SIZE / MfmaUtil / Occupancy for
// the real kernel. z removed next round.
// ---------------------------------------------------------------------------
struct GemmLds {
  union {
    struct { unsigned short A_s[128 * 128]; unsigned short B_s[128 * 128]; } ab;
    float c_s[128][132];
  };
};

__global__ __launch_bounds__(256) void gemm_kernel(const unsigned short* __restrict__ A,
                                                   const unsigned short* __restrict__ Bm,
                                                   float* __restrict__ Cc) {
  __shared__ GemmLds sh;
  unsigned short* A_s = sh.ab.A_s;
  unsigned short* B_s = sh.ab.B_s;
  int m0 = blockIdx.y * 128;
  int n0 = blockIdx.x * 128;
  int tid = threadIdx.x;

#pragma unroll
  for (int it = 0; it < 8; ++it) {
    int lin = it * 256 + tid;
    int row = lin >> 4, slot = lin & 15;
    int sw = slot ^ (row & 7);
    uint4 va = *(const uint4*)(A + ((size_t)(m0 + row)) * 128 + slot * 8);
    *(uint4*)(A_s + row * 128 + sw * 8) = va;
    uint4 vb = *(const uint4*)(Bm + ((size_t)(n0 + row)) * 128 + slot * 8);
    *(uint4*)(B_s + row * 128 + sw * 8) = vb;
  }
  __syncthreads();

  int lane = tid & 63;
  int w = tid >> 6;
  int wm = (w >> 1) * 64, wn = (w & 1) * 64;
  int lr = lane & 15, g = lane >> 4;

  v4f acc[4][4];
#pragma unroll
  for (int mf = 0; mf < 4; ++mf)
#pragma unroll
    for (int nf = 0; nf < 4; ++nf) {
      v4f z = {0.f, 0.f, 0.f, 0.f};
      acc[mf][nf] = z;
    }

#pragma unroll
  for (int ks = 0; ks < 4; ++ks) {
    int kg = ks * 4 + g;
    v8s a[4], bfr[4];
#pragma unroll
    for (int mf = 0; mf < 4; ++mf) {
      int row = wm + mf * 16 + lr;
      a[mf] = *(v8s*)(A_s + row * 128 + ((kg ^ (row & 7)) * 8));
    }
#pragma unroll
    for (int nf = 0; nf < 4; ++nf) {
      int row = wn + nf * 16 + lr;
      bfr[nf] = *(v8s*)(B_s + row * 128 + ((kg ^ (row & 7)) * 8));
    }
#pragma unroll
    for (int mf = 0; mf < 4; ++mf)
#pragma unroll
      for (int nf = 0; nf < 4; ++nf)
        acc[mf][nf] = __builtin_amdgcn_mfma_f32_16x16x32_bf16(a[mf], bfr[nf], acc[mf][nf], 0, 0, 0);
  }

  // ---- epilogue: acc -> LDS transpose, then nt v4f stores (v1 exact)
  __syncthreads();
#pragma unroll
  for (int mf = 0; mf < 4; ++mf)
#pragma unroll
    for (int reg = 0; reg < 4; ++reg) {
      int row = wm + mf * 16 + g * 4 + reg;
#pragma unroll
      for (int nf = 0; nf < 4; ++nf)
        sh.c_s[row][wn + nf * 16 + lr] = acc[mf][nf][reg];
    }
  __syncthreads();

  int slot = tid & 31;
  int rsub = tid >> 5;
  bool edge = (n0 + 128 > QQ);
#pragma unroll
  for (int it = 0; it < 16; ++it) {
    int row = it * 8 + rsub;
    int n = n0 + slot * 4;
    v4f v = *(v4f*)(&sh.c_s[row][slot * 4]);
    float* crow = Cc + (size_t)(m0 + row) * QQ;
    if (!edge) {
      __builtin_nontemporal_store(v, (v4f*)(crow + n));
    } else {
      if (n + 3 < QQ) {
        __builtin_nontemporal_store(v, (v4f*)(crow + n));
      } else {
        if (n + 0 < QQ) crow[n + 0] = v.x;
        if (n + 1 < QQ) crow[n + 1] = v.y;
        if (n + 2 < QQ) crow[n + 2] = v.z;
        if (n + 3 < QQ) crow[n + 3] = v.w;
      }
    }
  }
}

// ---------------------------------------------------------------------------
extern "C" void kernel_launch(void* const* d_in, const int* in_sizes, int n_in,
                              void* d_out, int out_size, void* d_ws, size_t ws_size,
                              hipStream_t stream) {
  (void)in_sizes; (void)n_in; (void)out_size; (void)ws_size;
  const int*   idx   = (const int*)d_in[0];
  const float* preW  = (const float*)d_in[1];
  const float* filtW = (const float*)d_in[2];
  const float* gateW = (const float*)d_in[3];
  const float* resW  = (const float*)d_in[4];
  const float* skipW = (const float*)d_in[5];
  const float* W1    = (const float*)d_in[6];
  const float* W2    = (const float*)d_in[7];
  float* out = (float*)d_out;

  char* ws = (char*)d_ws;
  float* skip = (float*)(ws);                              // 3,670,016 B
  unsigned short* h1  = (unsigned short*)(ws + 3670016);   // 1,835,008 B
  unsigned short* W2T = (unsigned short*)(ws + 5505024);   // 4,194,304 B  (~9.7 MB)

  w2t_kernel<<<dim3(NPAD / 64), 256, 0, stream>>>(W2, W2T);
  fused_layers_kernel<<<dim3(OUTW / WCH, BB), 1024, 0, stream>>>(idx, preW, filtW, gateW,
                                                                 resW, skipW, skip);
  h1_kernel<<<dim3(MROWS / 32), 256, 0, stream>>>(skip, W1, h1);
  // z=2 attribution launch: one dispatch, double work, identical output.
  gemm_kernel<<<dim3(NPAD / 128, MROWS / 128, 2), 256, 0, stream>>>(h1, W2T, out);
}

// Round 13
// 276.423 us; speedup vs baseline: 1.5742x; 1.5742x over previous
//
#include <hip/hip_runtime.h>
#include <stdint.h>

// Problem constants
#define BB 4
#define LL 2048
#define QQ 16293
#define RR 24
#define DD 32
#define SS 128
#define NLAYER 8
#define OUTW 1792
#define TT0 2047              // length of x after embedding (L-1)
#define MROWS (BB*OUTW)       // 7168
#define NPAD 16384            // padded Q for GEMM tiles
#define WCH 28                // skip rows per fused-layer block (64 blocks/batch)

typedef float v4f __attribute__((ext_vector_type(4)));
typedef short v8s __attribute__((ext_vector_type(8)));

static __device__ __forceinline__ unsigned short f2bf(float x) {
  unsigned int u = __float_as_uint(x);
  unsigned int r = (u + 0x7fffu + ((u >> 16) & 1u)) >> 16;
  return (unsigned short)r;
}

static __device__ __forceinline__ float fast_sigmoid(float z) {
  return __builtin_amdgcn_rcpf(1.0f + __expf(-z));
}
static __device__ __forceinline__ float fast_tanh(float z) {
  return 1.0f - 2.0f * __builtin_amdgcn_rcpf(1.0f + __expf(2.0f * z));
}

// ---------------------------------------------------------------------------
// Fused layers v3 (kept: saved ~30us in R12): all per-layer weights
// double-buffered in LDS, prefetched one layer ahead (T14 split).
// ---------------------------------------------------------------------------
__global__ __launch_bounds__(1024) void fused_layers_kernel(
    const int* __restrict__ idx, const float* __restrict__ preW,
    const float* __restrict__ filtW, const float* __restrict__ gateW,
    const float* __restrict__ resW, const float* __restrict__ skipW,
    float* __restrict__ skip_out) {
  int b = blockIdx.y;
  int j0 = blockIdx.x * WCH;
  int tid = (int)threadIdx.x;
  int lane = tid & 63;
  int w = __builtin_amdgcn_readfirstlane(tid >> 6);

  __shared__ float x_t[2][RR][66];
  __shared__ float out_s[64][33];
  __shared__ float wF[2][2 * RR * DD];
  __shared__ float wG[2][2 * RR * DD];
  __shared__ float wR[2][DD * RR];
  __shared__ float wS[2][DD * SS];

  for (int z = tid; z < 2 * RR * 2; z += 1024) {
    int bu = z & 1;
    int cc = 64 + ((z >> 1) & 1);
    int r = z >> 2;
    x_t[bu][r][cc] = 0.f;
  }

  float pf[8];
  {
    const float* Fs = filtW;
    const float* Gs = gateW;
    pf[0] = Fs[tid];
    pf[1] = (tid < 512) ? Fs[1024 + tid] : Gs[tid - 512];
    pf[2] = Gs[512 + tid];
    pf[3] = (tid < DD * RR) ? resW[tid] : 0.f;
    const float2* S2 = (const float2*)skipW;
#pragma unroll
    for (int k = 0; k < 2; ++k) {
      float2 v = S2[k * 1024 + tid];
      pf[4 + 2 * k] = v.x;
      pf[5 + 2 * k] = v.y;
    }
  }

  int tbase = j0 + 247;
  if (w < 12) {
    int t = tbase + lane;
    if (t > TT0 - 1) t = TT0 - 1;
    int i0 = idx[b * LL + t];
    int i1 = idx[b * LL + t + 1];
    const float* p0 = preW + (size_t)i0 * RR + 2 * w;
    const float* p1 = preW + (size_t)QQ * RR + (size_t)i1 * RR + 2 * w;
#pragma unroll
    for (int rr = 0; rr < 2; ++rr)
      x_t[0][2 * w + rr][lane] = p0[rr] + p1[rr];
  }

  {
    wF[0][tid] = pf[0];
    if (tid < 512) wF[0][1024 + tid] = pf[1]; else wG[0][tid - 512] = pf[1];
    wG[0][512 + tid] = pf[2];
    if (tid < DD * RR) wR[0][tid] = pf[3];
#pragma unroll
    for (int k = 0; k < 2; ++k) {
      wS[0][(k * 1024 + tid) * 2 + 0] = pf[4 + 2 * k];
      wS[0][(k * 1024 + tid) * 2 + 1] = pf[5 + 2 * k];
    }
  }

  float sk00 = 0.f, sk01 = 0.f, sk10 = 0.f, sk11 = 0.f;

  __syncthreads();

  for (int i = 0; i < NLAYER; ++i) {
    int cur = i & 1, nxt = cur ^ 1;
    int lmax = 62 - i;

    float xa[RR], xb[RR];
#pragma unroll
    for (int r = 0; r < RR; ++r) {
      xa[r] = x_t[cur][r][lane];
      xb[r] = x_t[cur][r][lane + 1];
    }
    float zf[2], zg[2];
#pragma unroll
    for (int dd = 0; dd < 2; ++dd) { zf[dd] = 0.f; zg[dd] = 0.f; }
#pragma unroll
    for (int r = 0; r < RR; ++r) {
#pragma unroll
      for (int dd = 0; dd < 2; ++dd) {
        int d = w * 2 + dd;
        zf[dd] = fmaf(xa[r], wF[cur][r * DD + d], zf[dd]);
        zf[dd] = fmaf(xb[r], wF[cur][RR * DD + r * DD + d], zf[dd]);
        zg[dd] = fmaf(xa[r], wG[cur][r * DD + d], zg[dd]);
        zg[dd] = fmaf(xb[r], wG[cur][RR * DD + r * DD + d], zg[dd]);
      }
    }
    if (lane <= lmax) {
#pragma unroll
      for (int dd = 0; dd < 2; ++dd)
        out_s[lane][w * 2 + dd] = fast_tanh(zf[dd]) * fast_sigmoid(zg[dd]);
    }
    __syncthreads();

    bool do_pf = (i + 1 < NLAYER);
    if (do_pf) {
      const float* Fs = filtW + (size_t)(i + 1) * 2 * RR * DD;
      const float* Gs = gateW + (size_t)(i + 1) * 2 * RR * DD;
      pf[0] = Fs[tid];
      pf[1] = (tid < 512) ? Fs[1024 + tid] : Gs[tid - 512];
      pf[2] = Gs[512 + tid];
      pf[3] = (tid < DD * RR) ? resW[(size_t)(i + 1) * DD * RR + tid] : 0.f;
      const float2* S2 = (const float2*)(skipW + (size_t)(i + 1) * DD * SS);
#pragma unroll
      for (int k = 0; k < 2; ++k) {
        float2 v = S2[k * 1024 + tid];
        pf[4 + 2 * k] = v.x;
        pf[5 + 2 * k] = v.y;
      }
    }

    if (w < 14) {
      int jr = 2 * w + 7 - i;
#pragma unroll
      for (int d = 0; d < DD; ++d) {
        float o0 = out_s[jr][d];
        float o1 = out_s[jr + 1][d];
        float wx = wS[cur][d * SS + 2 * lane];
        float wy = wS[cur][d * SS + 2 * lane + 1];
        sk00 = fmaf(o0, wx, sk00);
        sk01 = fmaf(o0, wy, sk01);
        sk10 = fmaf(o1, wx, sk10);
        sk11 = fmaf(o1, wy, sk11);
      }
    }

    if (w < 12 && lane <= lmax) {
#pragma unroll
      for (int rr = 0; rr < 2; ++rr) {
        int r = w * 2 + rr;
        float acc = x_t[cur][r][lane + 1];
#pragma unroll
        for (int d = 0; d < DD; ++d)
          acc = fmaf(out_s[lane][d], wR[cur][d * RR + r], acc);
        x_t[nxt][r][lane] = acc;
      }
    }

    if (do_pf) {
      wF[nxt][tid] = pf[0];
      if (tid < 512) wF[nxt][1024 + tid] = pf[1]; else wG[nxt][tid - 512] = pf[1];
      wG[nxt][512 + tid] = pf[2];
      if (tid < DD * RR) wR[nxt][tid] = pf[3];
#pragma unroll
      for (int k = 0; k < 2; ++k) {
        wS[nxt][(k * 1024 + tid) * 2 + 0] = pf[4 + 2 * k];
        wS[nxt][(k * 1024 + tid) * 2 + 1] = pf[5 + 2 * k];
      }
    }
    __syncthreads();
  }

  if (w < 14) {
    size_t base = ((size_t)b * OUTW + j0 + 2 * w) * SS + 2 * lane;
    float2 v0; v0.x = sk00; v0.y = sk01;
    float2 v1; v1.x = sk10; v1.y = sk11;
    *(float2*)(skip_out + base) = v0;
    *(float2*)(skip_out + base + SS) = v1;
  }
}

// ---------------------------------------------------------------------------
// h1 = relu(relu(skip_sum) @ post_W1), stored bf16  [7168][128] (unchanged)
// ---------------------------------------------------------------------------
__global__ __launch_bounds__(256) void h1_kernel(const float* __restrict__ skip_sum,
                                                 const float* __restrict__ W1,
                                                 unsigned short* __restrict__ h1) {
  int m0 = blockIdx.x * 32;
  int tc = threadIdx.x & 31;
  int tr = threadIdx.x >> 5;
  __shared__ float h_s[32][128];
#pragma unroll
  for (int it = 0; it < 16; ++it) {
    int lin = it * 256 + (int)threadIdx.x;
    int rrow = lin >> 7, d = lin & 127;
    float v = skip_sum[(size_t)(m0 + rrow) * SS + d];
    h_s[rrow][d] = v > 0.f ? v : 0.f;
  }
  __syncthreads();

  float acc[4][4];
#pragma unroll
  for (int rr = 0; rr < 4; ++rr)
#pragma unroll
    for (int c = 0; c < 4; ++c) acc[rr][c] = 0.f;

#pragma unroll 4
  for (int d = 0; d < 128; ++d) {
    float4 wv = *(const float4*)(W1 + (size_t)d * SS + tc * 4);
#pragma unroll
    for (int rr = 0; rr < 4; ++rr) {
      float hv = h_s[tr * 4 + rr][d];
      acc[rr][0] = fmaf(hv, wv.x, acc[rr][0]);
      acc[rr][1] = fmaf(hv, wv.y, acc[rr][1]);
      acc[rr][2] = fmaf(hv, wv.z, acc[rr][2]);
      acc[rr][3] = fmaf(hv, wv.w, acc[rr][3]);
    }
  }
#pragma unroll
  for (int rr = 0; rr < 4; ++rr) {
    int row = m0 + tr * 4 + rr;
    ushort4 u;
    u.x = f2bf(fmaxf(acc[rr][0], 0.f));
    u.y = f2bf(fmaxf(acc[rr][1], 0.f));
    u.z = f2bf(fmaxf(acc[rr][2], 0.f));
    u.w = f2bf(fmaxf(acc[rr][3], 0.f));
    *(ushort4*)(h1 + (size_t)row * SS + tc * 4) = u;
  }
}

// ---------------------------------------------------------------------------
// W2T: transpose post_W2 [128][16293] -> bf16 [16384][128], zero-padded
// ---------------------------------------------------------------------------
__global__ __launch_bounds__(256) void w2t_kernel(const float* __restrict__ W2,
                                                  unsigned short* __restrict__ W2T) {
  int n0 = blockIdx.x * 64;
  __shared__ float t_s[64][129];
#pragma unroll
  for (int it = 0; it < 32; ++it) {
    int lin = it * 256 + (int)threadIdx.x;
    int k = lin >> 6, nn = lin & 63;
    int n = n0 + nn;
    t_s[nn][k] = (n < QQ) ? W2[(size_t)k * QQ + n] : 0.f;
  }
  __syncthreads();
#pragma unroll
  for (int it = 0; it < 4; ++it) {
    int lin = it * 256 + (int)threadIdx.x;
    int nn = lin >> 4, slot = lin & 15;
    v8s val;
#pragma unroll
    for (int jj = 0; jj < 8; ++jj) val[jj] = (short)f2bf(t_s[nn][slot * 8 + jj]);
    *(v8s*)(W2T + ((size_t)(n0 + nn)) * 128 + slot * 8) = val;
  }
}

// ---------------------------------------------------------------------------
// logits = h1 @ W2 (bf16 MFMA, fp32 accum). v7: OCCUPANCY fix per R12
// counters (Occ 19.6%, everything idle, no write amplification).
// LDS diet: B_s 32KB (staged, XOR swizzle) + separate c_s[32][132] 16.9KB
// = 49.7KB -> 3 blocks/CU (was 67.6KB -> 2). A fragments load DIRECTLY
// global->VGPR (A is 1.8MB, L2-resident; 16 rows x 64B per instruction).
// Epilogue: 4 passes of 32 rows through c_s; store shape identical to v1
// (nt v4f, 512B runs per wave). Fragment k-mapping unchanged.
// ---------------------------------------------------------------------------
__global__ __launch_bounds__(256) void gemm_kernel(const unsigned short* __restrict__ A,
                                                   const unsigned short* __restrict__ Bm,
                                                   float* __restrict__ Cc) {
  __shared__ unsigned short B_s[128 * 128];   // 32KB
  __shared__ float c_s[32][132];              // 16.9KB
  int m0 = blockIdx.y * 128;
  int n0 = blockIdx.x * 128;
  int tid = threadIdx.x;
  int lane = tid & 63;
  int w = tid >> 6;
  int wm = (w >> 1) * 64, wn = (w & 1) * 64;
  int lr = lane & 15, g = lane >> 4;

  // ---- stage B tile into LDS (coalesced, XOR swizzle)
#pragma unroll
  for (int it = 0; it < 8; ++it) {
    int lin = it * 256 + tid;
    int row = lin >> 4, slot = lin & 15;
    int sw = slot ^ (row & 7);
    uint4 vb = *(const uint4*)(Bm + ((size_t)(n0 + row)) * 128 + slot * 8);
    *(uint4*)(B_s + row * 128 + sw * 8) = vb;
  }

  // ---- A fragments direct global->VGPR (issued alongside B staging)
  v8s a[4][4];
#pragma unroll
  for (int mf = 0; mf < 4; ++mf)
#pragma unroll
    for (int ks = 0; ks < 4; ++ks)
      a[mf][ks] = *(const v8s*)(A + ((size_t)(m0 + wm + mf * 16 + lr)) * 128 + (ks * 4 + g) * 8);

  __syncthreads();

  v4f acc[4][4];
#pragma unroll
  for (int mf = 0; mf < 4; ++mf)
#pragma unroll
    for (int nf = 0; nf < 4; ++nf) {
      v4f z = {0.f, 0.f, 0.f, 0.f};
      acc[mf][nf] = z;
    }

#pragma unroll
  for (int ks = 0; ks < 4; ++ks) {
    int kg = ks * 4 + g;
    v8s bfr[4];
#pragma unroll
    for (int nf = 0; nf < 4; ++nf) {
      int row = wn + nf * 16 + lr;
      bfr[nf] = *(v8s*)(B_s + row * 128 + ((kg ^ (row & 7)) * 8));
    }
#pragma unroll
    for (int mf = 0; mf < 4; ++mf)
#pragma unroll
      for (int nf = 0; nf < 4; ++nf)
        acc[mf][nf] = __builtin_amdgcn_mfma_f32_16x16x32_bf16(a[mf][ks], bfr[nf], acc[mf][nf], 0, 0, 0);
  }

  // ---- epilogue: 4 passes of 32 rows through c_s
  int slot = tid & 31;
  int rsub = tid >> 5;
  bool edge = (n0 + 128 > QQ);
#pragma unroll
  for (int p = 0; p < 4; ++p) {
    // write phase: waves with wm == (p>>1)*64 own this pass's rows
    if ((w >> 1) == (p >> 1)) {
#pragma unroll
      for (int mfo = 0; mfo < 2; ++mfo) {
        int mf = (p & 1) * 2 + mfo;
#pragma unroll
        for (int reg = 0; reg < 4; ++reg) {
          int lrow = mfo * 16 + g * 4 + reg;
#pragma unroll
          for (int nf = 0; nf < 4; ++nf)
            c_s[lrow][wn + nf * 16 + lr] = acc[mf][nf][reg];
        }
      }
    }
    __syncthreads();

    // store phase: 32 rows x 128 cols, nt v4f (512B runs per wave)
#pragma unroll
    for (int it = 0; it < 4; ++it) {
      int lrow = it * 8 + rsub;
      int row = p * 32 + lrow;
      int n = n0 + slot * 4;
      v4f v = *(v4f*)(&c_s[lrow][slot * 4]);
      float* crow = Cc + (size_t)(m0 + row) * QQ;
      if (!edge) {
        __builtin_nontemporal_store(v, (v4f*)(crow + n));
      } else if (n + 3 < QQ) {
        __builtin_nontemporal_store(v, (v4f*)(crow + n));
      } else {
        if (n + 0 < QQ) crow[n + 0] = v.x;
        if (n + 1 < QQ) crow[n + 1] = v.y;
        if (n + 2 < QQ) crow[n + 2] = v.z;
        if (n + 3 < QQ) crow[n + 3] = v.w;
      }
    }
    if (p < 3) __syncthreads();   // c_s reads done before next pass writes
  }
}

// ---------------------------------------------------------------------------
extern "C" void kernel_launch(void* const* d_in, const int* in_sizes, int n_in,
                              void* d_out, int out_size, void* d_ws, size_t ws_size,
                              hipStream_t stream) {
  (void)in_sizes; (void)n_in; (void)out_size; (void)ws_size;
  const int*   idx   = (const int*)d_in[0];
  const float* preW  = (const float*)d_in[1];
  const float* filtW = (const float*)d_in[2];
  const float* gateW = (const float*)d_in[3];
  const float* resW  = (const float*)d_in[4];
  const float* skipW = (const float*)d_in[5];
  const float* W1    = (const float*)d_in[6];
  const float* W2    = (const float*)d_in[7];
  float* out = (float*)d_out;

  char* ws = (char*)d_ws;
  float* skip = (float*)(ws);                              // 3,670,016 B
  unsigned short* h1  = (unsigned short*)(ws + 3670016);   // 1,835,008 B
  unsigned short* W2T = (unsigned short*)(ws + 5505024);   // 4,194,304 B  (~9.7 MB)

  w2t_kernel<<<dim3(NPAD / 64), 256, 0, stream>>>(W2, W2T);
  fused_layers_kernel<<<dim3(OUTW / WCH, BB), 1024, 0, stream>>>(idx, preW, filtW, gateW,
                                                                 resW, skipW, skip);
  h1_kernel<<<dim3(MROWS / 32), 256, 0, stream>>>(skip, W1, h1);
  gemm_kernel<<<dim3(NPAD / 128, MROWS / 128), 256, 0, stream>>>(h1, W2T, out);
}